// Round 1
// baseline (421.682 us; speedup 1.0000x reference)
//
#include <hip/hip_runtime.h>
#include <hip/hip_bf16.h>

typedef __attribute__((ext_vector_type(8))) short s16x8;
typedef __attribute__((ext_vector_type(4))) float f32x4;

#define MFMA(a,b,c) __builtin_amdgcn_mfma_f32_16x16x32_bf16((a),(b),(c),0,0,0)

__device__ __forceinline__ unsigned short bf16_rne(float f){
  unsigned int u = __float_as_uint(f);
  return (unsigned short)((u + 0x7FFFu + ((u >> 16) & 1u)) >> 16);
}
__device__ __forceinline__ float bf16_f32(unsigned short h){
  return __uint_as_float(((unsigned int)h) << 16);
}
__device__ __forceinline__ void split_hl(float f, short& hi, short& lo){
  unsigned short h = bf16_rne(f);
  float rem = f - bf16_f32(h);
  hi = (short)h;
  lo = (short)bf16_rne(rem);
}

// build hi/lo bf16 A-fragments from 8 consecutive fp32 values
__device__ __forceinline__ void build_frag(const float* p, s16x8& fh, s16x8& fl){
  float4 v0 = *(const float4*)p;
  float4 v1 = *(const float4*)(p + 4);
  float vv[8] = {v0.x, v0.y, v0.z, v0.w, v1.x, v1.y, v1.z, v1.w};
  #pragma unroll
  for(int j = 0; j < 8; ++j){ short h, l; split_hl(vv[j], h, l); fh[j] = h; fl[j] = l; }
}

__device__ __forceinline__ float sigm(float x){ return 1.0f / (1.0f + __expf(-x)); }
__device__ __forceinline__ float tanh_fast(float x){ return 1.0f - 2.0f / (__expf(2.0f * x) + 1.0f); }

// ---------------------------------------------------------------------------
// Kernel 1: trunk.  x2 = relu(LN(concat(relu(LN(obs@W1+b1)),act)@W2+b2))
// stored as split bf16 (hi/lo planes).  64 rows / block, 256 threads (4 waves),
// each wave: 16 rows x 64 cols via 16x16x32 MFMA with hi/lo 3-product split.
// ---------------------------------------------------------------------------
__global__ __launch_bounds__(256) void trunk_kernel(
    const float* __restrict__ obs, const float* __restrict__ actg,
    const float* __restrict__ W1, const float* __restrict__ b1,
    const float* __restrict__ g1, const float* __restrict__ be1,
    const float* __restrict__ W2, const float* __restrict__ b2,
    const float* __restrict__ g2, const float* __restrict__ be2,
    unsigned short* __restrict__ x2h, unsigned short* __restrict__ x2l)
{
  __shared__ __align__(16) float obs_t[64][132];
  __shared__ __align__(16) float x1_t[64][68];
  __shared__ __align__(16) float act_t[64][36];
  __shared__ __align__(16) short w1p[2][4][4][64][8];
  __shared__ __align__(16) short w2p[2][3][4][64][8];

  const int tid = threadIdx.x;
  const int r0 = blockIdx.x * 64;

  // stage obs tile (64 x 128 fp32, contiguous 32KB) and action tile (64 x 32)
  #pragma unroll
  for(int i = 0; i < 8; ++i){
    int idx = tid + i * 256;            // float4 index
    int row = idx >> 5;
    int c4  = (idx & 31) * 4;
    *(float4*)&obs_t[row][c4] = *(const float4*)&obs[(size_t)(r0 + row) * 128 + c4];
  }
  #pragma unroll
  for(int i = 0; i < 2; ++i){
    int idx = tid + i * 256;
    int row = idx >> 3;
    int c4  = (idx & 7) * 4;
    *(float4*)&act_t[row][c4] = *(const float4*)&actg[(size_t)(r0 + row) * 32 + c4];
  }
  // pack W1 into B-fragment order (hi/lo)
  for(int idx = tid; idx < 8192; idx += 256){
    int j = idx & 7, l = (idx >> 3) & 63, nt = (idx >> 9) & 3, kk = idx >> 11;
    int k = kk * 32 + 8 * (l >> 4) + j;
    int col = nt * 16 + (l & 15);
    short h, lo; split_hl(W1[k * 64 + col], h, lo);
    w1p[0][kk][nt][l][j] = h; w1p[1][kk][nt][l][j] = lo;
  }
  // pack W2 (96 rows -> kk<3)
  for(int idx = tid; idx < 6144; idx += 256){
    int j = idx & 7, l = (idx >> 3) & 63, nt = (idx >> 9) & 3, kk = idx >> 11;
    int k = kk * 32 + 8 * (l >> 4) + j;
    int col = nt * 16 + (l & 15);
    short h, lo; split_hl(W2[k * 64 + col], h, lo);
    w2p[0][kk][nt][l][j] = h; w2p[1][kk][nt][l][j] = lo;
  }
  __syncthreads();

  const int w = tid >> 6, lane = tid & 63;
  const int l15 = lane & 15, l4 = lane >> 4;

  float b1v[4], g1v[4], be1v[4], b2v[4], g2v[4], be2v[4];
  #pragma unroll
  for(int nt = 0; nt < 4; ++nt){
    int col = nt * 16 + l15;
    b1v[nt] = b1[col]; g1v[nt] = g1[col]; be1v[nt] = be1[col];
    b2v[nt] = b2[col]; g2v[nt] = g2[col]; be2v[nt] = be2[col];
  }

  // ---- GEMM1: obs @ W1 ----
  f32x4 acc1[4] = {{0,0,0,0},{0,0,0,0},{0,0,0,0},{0,0,0,0}};
  #pragma unroll
  for(int kk = 0; kk < 4; ++kk){
    s16x8 ah, al;
    build_frag(&obs_t[w * 16 + l15][8 * l4 + 32 * kk], ah, al);
    #pragma unroll
    for(int nt = 0; nt < 4; ++nt){
      s16x8 bh = *(const s16x8*)&w1p[0][kk][nt][lane][0];
      s16x8 bl = *(const s16x8*)&w1p[1][kk][nt][lane][0];
      acc1[nt] = MFMA(ah, bh, acc1[nt]);
      acc1[nt] = MFMA(ah, bl, acc1[nt]);
      acc1[nt] = MFMA(al, bh, acc1[nt]);
    }
  }

  // ---- LN1 + relu -> x1_t ----
  float x1s[4][4]; // [r][nt]
  #pragma unroll
  for(int r = 0; r < 4; ++r){
    float v[4];
    #pragma unroll
    for(int nt = 0; nt < 4; ++nt) v[nt] = acc1[nt][r] + b1v[nt];
    float s = (v[0] + v[1]) + (v[2] + v[3]);
    #pragma unroll
    for(int mm = 1; mm < 16; mm <<= 1) s += __shfl_xor(s, mm);
    float mean = s * (1.0f / 64.0f);
    float d[4]; float q = 0.f;
    #pragma unroll
    for(int nt = 0; nt < 4; ++nt){ d[nt] = v[nt] - mean; q += d[nt] * d[nt]; }
    #pragma unroll
    for(int mm = 1; mm < 16; mm <<= 1) q += __shfl_xor(q, mm);
    float rstd = rsqrtf(q * (1.0f / 64.0f) + 1e-12f);
    #pragma unroll
    for(int nt = 0; nt < 4; ++nt) x1s[r][nt] = fmaxf(0.f, d[nt] * rstd * g1v[nt] + be1v[nt]);
  }
  #pragma unroll
  for(int r = 0; r < 4; ++r){
    int row = w * 16 + l4 * 4 + r;
    #pragma unroll
    for(int nt = 0; nt < 4; ++nt) x1_t[row][nt * 16 + l15] = x1s[r][nt];
  }
  __syncthreads();

  // ---- GEMM2: concat(x1, act) @ W2  (K = 96 -> kk 0,1 from x1, kk 2 from act)
  f32x4 acc2[4] = {{0,0,0,0},{0,0,0,0},{0,0,0,0},{0,0,0,0}};
  #pragma unroll
  for(int kk = 0; kk < 3; ++kk){
    s16x8 ah, al;
    if(kk < 2) build_frag(&x1_t[w * 16 + l15][8 * l4 + 32 * kk], ah, al);
    else       build_frag(&act_t[w * 16 + l15][8 * l4], ah, al);
    #pragma unroll
    for(int nt = 0; nt < 4; ++nt){
      s16x8 bh = *(const s16x8*)&w2p[0][kk][nt][lane][0];
      s16x8 bl = *(const s16x8*)&w2p[1][kk][nt][lane][0];
      acc2[nt] = MFMA(ah, bh, acc2[nt]);
      acc2[nt] = MFMA(ah, bl, acc2[nt]);
      acc2[nt] = MFMA(al, bh, acc2[nt]);
    }
  }

  // ---- LN2 + relu -> split bf16 store ----
  #pragma unroll
  for(int r = 0; r < 4; ++r){
    float v[4];
    #pragma unroll
    for(int nt = 0; nt < 4; ++nt) v[nt] = acc2[nt][r] + b2v[nt];
    float s = (v[0] + v[1]) + (v[2] + v[3]);
    #pragma unroll
    for(int mm = 1; mm < 16; mm <<= 1) s += __shfl_xor(s, mm);
    float mean = s * (1.0f / 64.0f);
    float d[4]; float q = 0.f;
    #pragma unroll
    for(int nt = 0; nt < 4; ++nt){ d[nt] = v[nt] - mean; q += d[nt] * d[nt]; }
    #pragma unroll
    for(int mm = 1; mm < 16; mm <<= 1) q += __shfl_xor(q, mm);
    float rstd = rsqrtf(q * (1.0f / 64.0f) + 1e-12f);
    size_t rowg = (size_t)(r0 + w * 16 + l4 * 4 + r);
    #pragma unroll
    for(int nt = 0; nt < 4; ++nt){
      float xv = fmaxf(0.f, d[nt] * rstd * g2v[nt] + be2v[nt]);
      short hi, lo; split_hl(xv, hi, lo);
      x2h[rowg * 64 + nt * 16 + l15] = (unsigned short)hi;
      x2l[rowg * 64 + nt * 16 + l15] = (unsigned short)lo;
    }
  }
}

// ---------------------------------------------------------------------------
// Kernel 2: LSTM scan (fw & bw), 32 sequences / block, 512 threads (8 waves).
// wave (m,dj): m = seq half (16 rows), dj = 16-wide slice of H.
// Per step: z[s][g] = [x_t | h] @ W + b via split-bf16 MFMA (W frags live in
// registers), gates in fp32, and the wx/wp dots folded in (h never stored).
// ---------------------------------------------------------------------------
__global__ __launch_bounds__(512) void lstm_kernel(
    const unsigned short* __restrict__ x2h, const unsigned short* __restrict__ x2l,
    const float* __restrict__ Wf, const float* __restrict__ bfv,
    const float* __restrict__ Wb, const float* __restrict__ bbv,
    const float* __restrict__ wx, const float* __restrict__ wp,
    float* __restrict__ xs_g, float* __restrict__ ps_g)
{
  __shared__ __align__(16) unsigned short x_lds_h[32][72];
  __shared__ __align__(16) unsigned short x_lds_l[32][72];
  __shared__ __align__(16) unsigned short h_lds_h[32][72];
  __shared__ __align__(16) unsigned short h_lds_l[32][72];
  __shared__ float xs_part[4][32];
  __shared__ float ps_part[4][32];

  const int tid = threadIdx.x;
  const int dir = blockIdx.y;
  const int b0 = blockIdx.x * 32;
  const float* W    = dir ? Wb  : Wf;
  const float* bias = dir ? bbv : bfv;

  const int w = tid >> 6, lane = tid & 63, l15 = lane & 15, l4 = lane >> 4;
  const int m = w >> 2, dj = w & 3;

  float biasv[4];
  #pragma unroll
  for(int gi = 0; gi < 4; ++gi) biasv[gi] = bias[gi * 64 + dj * 16 + l15];
  const float wxv = wx[dj * 16 + l15];
  const float wpv = wp[dj * 16 + l15];

  // W B-fragments (hi/lo) in registers, reused all 64 steps.
  s16x8 Bh[4][4], Bl[4][4];
  #pragma unroll
  for(int gi = 0; gi < 4; ++gi){
    int col = gi * 64 + dj * 16 + l15;
    #pragma unroll
    for(int kk = 0; kk < 4; ++kk){
      #pragma unroll
      for(int j = 0; j < 8; ++j){
        int k = kk * 32 + 8 * l4 + j;
        short h, lo; split_hl(W[k * 256 + col], h, lo);
        Bh[gi][kk][j] = h; Bl[gi][kk][j] = lo;
      }
    }
  }

  // zero h state planes
  for(int i = tid; i < 32 * 72; i += 512){ (&h_lds_h[0][0])[i] = 0; (&h_lds_l[0][0])[i] = 0; }

  const int s_pf = tid >> 4, c4_pf = (tid & 15) * 4;
  int t0 = dir ? 63 : 0;
  ushort4 xpre_h = *(const ushort4*)&x2h[((size_t)(b0 + s_pf) * 64 + t0) * 64 + c4_pf];
  ushort4 xpre_l = *(const ushort4*)&x2l[((size_t)(b0 + s_pf) * 64 + t0) * 64 + c4_pf];

  float c[4] = {0.f, 0.f, 0.f, 0.f};

  for(int tau = 0; tau < 64; ++tau){
    *(ushort4*)&x_lds_h[s_pf][c4_pf] = xpre_h;
    *(ushort4*)&x_lds_l[s_pf][c4_pf] = xpre_l;
    __syncthreads();
    if(tau < 63){
      int tn = dir ? 62 - tau : tau + 1;
      xpre_h = *(const ushort4*)&x2h[((size_t)(b0 + s_pf) * 64 + tn) * 64 + c4_pf];
      xpre_l = *(const ushort4*)&x2l[((size_t)(b0 + s_pf) * 64 + tn) * 64 + c4_pf];
    }
    // A fragments (pre-split, straight b128 reads)
    s16x8 Axh[2], Axl[2], Ahh[2], Ahl[2];
    #pragma unroll
    for(int kk = 0; kk < 2; ++kk){
      Axh[kk] = *(const s16x8*)&x_lds_h[m * 16 + l15][8 * l4 + 32 * kk];
      Axl[kk] = *(const s16x8*)&x_lds_l[m * 16 + l15][8 * l4 + 32 * kk];
      Ahh[kk] = *(const s16x8*)&h_lds_h[m * 16 + l15][8 * l4 + 32 * kk];
      Ahl[kk] = *(const s16x8*)&h_lds_l[m * 16 + l15][8 * l4 + 32 * kk];
    }
    f32x4 acc[4] = {{0,0,0,0},{0,0,0,0},{0,0,0,0},{0,0,0,0}};
    #pragma unroll
    for(int gi = 0; gi < 4; ++gi){
      #pragma unroll
      for(int kk = 0; kk < 2; ++kk){
        acc[gi] = MFMA(Axh[kk], Bh[gi][kk],     acc[gi]);
        acc[gi] = MFMA(Axh[kk], Bl[gi][kk],     acc[gi]);
        acc[gi] = MFMA(Axl[kk], Bh[gi][kk],     acc[gi]);
        acc[gi] = MFMA(Ahh[kk], Bh[gi][kk + 2], acc[gi]);
        acc[gi] = MFMA(Ahh[kk], Bl[gi][kk + 2], acc[gi]);
        acc[gi] = MFMA(Ahl[kk], Bh[gi][kk + 2], acc[gi]);
      }
    }
    // gates + state update (order i, j, f, o)
    float hv[4];
    #pragma unroll
    for(int r = 0; r < 4; ++r){
      float zi = acc[0][r] + biasv[0];
      float zj = acc[1][r] + biasv[1];
      float zf = acc[2][r] + biasv[2];
      float zo = acc[3][r] + biasv[3];
      float cf = c[r] * sigm(zf + 1.0f) + sigm(zi) * tanh_fast(zj);
      c[r] = cf;
      hv[r] = tanh_fast(cf) * sigm(zo);
    }
    // fold in the wx/wp dots: reduce over d (16 lanes) then across dj waves
    float px[4], pp[4];
    #pragma unroll
    for(int r = 0; r < 4; ++r){ px[r] = hv[r] * wxv; pp[r] = hv[r] * wpv; }
    #pragma unroll
    for(int mm = 1; mm < 16; mm <<= 1){
      #pragma unroll
      for(int r = 0; r < 4; ++r){ px[r] += __shfl_xor(px[r], mm); pp[r] += __shfl_xor(pp[r], mm); }
    }
    if(l15 == 0){
      #pragma unroll
      for(int r = 0; r < 4; ++r){
        int s = m * 16 + l4 * 4 + r;
        xs_part[dj][s] = px[r];
        ps_part[dj][s] = pp[r];
      }
    }
    __syncthreads();
    // write h (split bf16) for next step's A fragments
    #pragma unroll
    for(int r = 0; r < 4; ++r){
      int s = m * 16 + l4 * 4 + r;
      short hi, lo; split_hl(hv[r], hi, lo);
      h_lds_h[s][dj * 16 + l15] = (unsigned short)hi;
      h_lds_l[s][dj * 16 + l15] = (unsigned short)lo;
    }
    // deterministic cross-wave sum + global store of xs/ps at time t_x
    int t_x = dir ? 63 - tau : tau;
    if(tid < 32){
      float xv = (xs_part[0][tid] + xs_part[1][tid]) + (xs_part[2][tid] + xs_part[3][tid]);
      float pv = (ps_part[0][tid] + ps_part[1][tid]) + (ps_part[2][tid] + ps_part[3][tid]);
      size_t idx = (size_t)dir * 262144 + (size_t)(b0 + tid) * 64 + t_x;
      xs_g[idx] = xv;
      ps_g[idx] = pv;
    }
  }
}

// ---------------------------------------------------------------------------
// Kernel 3: head.  One wave per output row (lane = timestep).
// out[r] = sum_t softmax(relu(LN(ps)) @ W3 + b3)[t] * xs[t]
// ---------------------------------------------------------------------------
__global__ __launch_bounds__(256) void final_kernel(
    const float* __restrict__ xs_g, const float* __restrict__ ps_g,
    const float* __restrict__ bx, const float* __restrict__ bp,
    const float* __restrict__ gp, const float* __restrict__ bep,
    const float* __restrict__ W3, const float* __restrict__ b3,
    float* __restrict__ out)
{
  __shared__ float p_sh[4][68];
  const int tid = threadIdx.x, w = tid >> 6, lane = tid & 63;
  const int row = blockIdx.x * 4 + w;
  float xsv = xs_g[(size_t)row * 64 + lane] + bx[0];
  float psv = ps_g[(size_t)row * 64 + lane] + bp[0];
  float s = psv;
  #pragma unroll
  for(int mm = 1; mm < 64; mm <<= 1) s += __shfl_xor(s, mm);
  float mean = s * (1.f / 64.f);
  float d = psv - mean;
  float q = d * d;
  #pragma unroll
  for(int mm = 1; mm < 64; mm <<= 1) q += __shfl_xor(q, mm);
  float rstd = rsqrtf(q * (1.f / 64.f) + 1e-12f);
  float p = fmaxf(0.f, d * rstd * gp[lane] + bep[lane]);
  p_sh[w][lane] = p;
  __syncthreads();
  float logit = b3[lane];
  #pragma unroll 8
  for(int t = 0; t < 64; ++t) logit += p_sh[w][t] * W3[t * 64 + lane];
  float mx = logit;
  #pragma unroll
  for(int mm = 1; mm < 64; mm <<= 1) mx = fmaxf(mx, __shfl_xor(mx, mm));
  float e = __expf(logit - mx);
  float se = e;
  #pragma unroll
  for(int mm = 1; mm < 64; mm <<= 1) se += __shfl_xor(se, mm);
  float contrib = (e / se) * xsv;
  #pragma unroll
  for(int mm = 1; mm < 64; mm <<= 1) contrib += __shfl_xor(contrib, mm);
  if(lane == 0) out[row] = contrib;
}

extern "C" void kernel_launch(void* const* d_in, const int* in_sizes, int n_in,
                              void* d_out, int out_size, void* d_ws, size_t ws_size,
                              hipStream_t stream)
{
  (void)in_sizes; (void)n_in; (void)out_size; (void)ws_size;
  const float* obs = (const float*)d_in[0];
  const float* act = (const float*)d_in[1];
  const float* W1  = (const float*)d_in[2];
  const float* b1  = (const float*)d_in[3];
  const float* g1  = (const float*)d_in[4];
  const float* be1 = (const float*)d_in[5];
  const float* W2  = (const float*)d_in[6];
  const float* b2  = (const float*)d_in[7];
  const float* g2  = (const float*)d_in[8];
  const float* be2 = (const float*)d_in[9];
  const float* Wf  = (const float*)d_in[10];
  const float* bfv = (const float*)d_in[11];
  const float* Wb  = (const float*)d_in[12];
  const float* bbv = (const float*)d_in[13];
  const float* wx  = (const float*)d_in[14];
  const float* bx  = (const float*)d_in[15];
  const float* wp  = (const float*)d_in[16];
  const float* bp  = (const float*)d_in[17];
  const float* gp  = (const float*)d_in[18];
  const float* bep = (const float*)d_in[19];
  const float* W3  = (const float*)d_in[20];
  const float* b3  = (const float*)d_in[21];

  unsigned short* x2h = (unsigned short*)d_ws;                         // 262144*64
  unsigned short* x2l = x2h + (size_t)262144 * 64;                     // 262144*64
  float* xs_g = (float*)(x2l + (size_t)262144 * 64);                   // 2*4096*64
  float* ps_g = xs_g + (size_t)2 * 4096 * 64;                          // 2*4096*64
  float* outf = (float*)d_out;

  trunk_kernel<<<4096, 256, 0, stream>>>(obs, act, W1, b1, g1, be1, W2, b2, g2, be2, x2h, x2l);
  lstm_kernel<<<dim3(128, 2), 512, 0, stream>>>(x2h, x2l, Wf, bfv, Wb, bbv, wx, wp, xs_g, ps_g);
  final_kernel<<<2048, 256, 0, stream>>>(xs_g, ps_g, bx, bp, gp, bep, W3, b3, outf);
}

// Round 2
// 247.663 us; speedup vs baseline: 1.7026x; 1.7026x over previous
//
#include <hip/hip_runtime.h>
#include <hip/hip_bf16.h>

typedef __attribute__((ext_vector_type(8))) short s16x8;
typedef __attribute__((ext_vector_type(4))) float f32x4;

#define MFMA(a,b,c) __builtin_amdgcn_mfma_f32_16x16x32_bf16((a),(b),(c),0,0,0)

__device__ __forceinline__ unsigned short bf16_rne(float f){
  unsigned int u = __float_as_uint(f);
  return (unsigned short)((u + 0x7FFFu + ((u >> 16) & 1u)) >> 16);
}
__device__ __forceinline__ float bf16_f32(unsigned short h){
  return __uint_as_float(((unsigned int)h) << 16);
}
__device__ __forceinline__ void split_hl(float f, short& hi, short& lo){
  unsigned short h = bf16_rne(f);
  float rem = f - bf16_f32(h);
  hi = (short)h;
  lo = (short)bf16_rne(rem);
}

// build hi/lo bf16 A-fragments from 8 consecutive fp32 values
__device__ __forceinline__ void build_frag(const float* p, s16x8& fh, s16x8& fl){
  float4 v0 = *(const float4*)p;
  float4 v1 = *(const float4*)(p + 4);
  float vv[8] = {v0.x, v0.y, v0.z, v0.w, v1.x, v1.y, v1.z, v1.w};
  #pragma unroll
  for(int j = 0; j < 8; ++j){ short h, l; split_hl(vv[j], h, l); fh[j] = h; fl[j] = l; }
}

__device__ __forceinline__ float sigm(float x){ return 1.0f / (1.0f + __expf(-x)); }
__device__ __forceinline__ float tanh_fast(float x){ return 1.0f - 2.0f / (__expf(2.0f * x) + 1.0f); }

// ---------------------------------------------------------------------------
// Kernel 0: pack all weights into fragment-ordered split-bf16 planes (once).
// w1p: [2][4kk][4nt][64lane][8j]   (8192 per plane)
// w2p: [2][3kk][4nt][64lane][8j]   (6144 per plane)
// wfp/wbp: [2][4gi][4kk][4dj][64lane][8j] (32768 per plane)
// ---------------------------------------------------------------------------
__global__ __launch_bounds__(256) void pack_kernel(
    const float* __restrict__ W1, const float* __restrict__ W2,
    const float* __restrict__ Wf, const float* __restrict__ Wb,
    unsigned short* __restrict__ w1p, unsigned short* __restrict__ w2p,
    unsigned short* __restrict__ wfp, unsigned short* __restrict__ wbp)
{
  int id = blockIdx.x * 256 + threadIdx.x;
  if(id < 8192){
    int t = id;
    int j = t & 7, lane = (t >> 3) & 63, nt = (t >> 9) & 3, kk = t >> 11;
    int k = kk * 32 + 8 * (lane >> 4) + j;
    int col = nt * 16 + (lane & 15);
    short h, l; split_hl(W1[k * 64 + col], h, l);
    w1p[t] = (unsigned short)h; w1p[8192 + t] = (unsigned short)l;
  } else if(id < 14336){
    int t = id - 8192;
    int j = t & 7, lane = (t >> 3) & 63, nt = (t >> 9) & 3, kk = t >> 11;
    int k = kk * 32 + 8 * (lane >> 4) + j;
    int col = nt * 16 + (lane & 15);
    short h, l; split_hl(W2[k * 64 + col], h, l);
    w2p[t] = (unsigned short)h; w2p[6144 + t] = (unsigned short)l;
  } else if(id < 47104){
    int t = id - 14336;
    int j = t & 7, lane = (t >> 3) & 63, dj = (t >> 9) & 3, kk = (t >> 11) & 3, gi = t >> 13;
    int k = kk * 32 + 8 * (lane >> 4) + j;
    int col = gi * 64 + dj * 16 + (lane & 15);
    short h, l; split_hl(Wf[k * 256 + col], h, l);
    wfp[t] = (unsigned short)h; wfp[32768 + t] = (unsigned short)l;
  } else if(id < 79872){
    int t = id - 47104;
    int j = t & 7, lane = (t >> 3) & 63, dj = (t >> 9) & 3, kk = (t >> 11) & 3, gi = t >> 13;
    int k = kk * 32 + 8 * (lane >> 4) + j;
    int col = gi * 64 + dj * 16 + (lane & 15);
    short h, l; split_hl(Wb[k * 256 + col], h, l);
    wbp[t] = (unsigned short)h; wbp[32768 + t] = (unsigned short)l;
  }
}

// ---------------------------------------------------------------------------
// Kernel 1: trunk.  x2 = relu(LN(concat(relu(LN(obs@W1+b1)),act)@W2+b2))
// stored as split bf16 (hi/lo planes).  64 rows / block, 256 threads (4 waves).
// A-fragments straight from global (coalesced 128B row segments); B-fragments
// straight from packed global (coalesced 16B/lane, L1/L2-resident).
// Only LDS: the 17KB x1 transit buffer.
// ---------------------------------------------------------------------------
__global__ __launch_bounds__(256) void trunk_kernel(
    const float* __restrict__ obs, const float* __restrict__ actg,
    const float* __restrict__ b1, const float* __restrict__ g1, const float* __restrict__ be1,
    const float* __restrict__ b2, const float* __restrict__ g2, const float* __restrict__ be2,
    const unsigned short* __restrict__ w1p, const unsigned short* __restrict__ w2p,
    unsigned short* __restrict__ x2h, unsigned short* __restrict__ x2l)
{
  __shared__ __align__(16) float x1_t[64][68];

  const int tid = threadIdx.x;
  const int r0 = blockIdx.x * 64;
  const int w = tid >> 6, lane = tid & 63;
  const int l15 = lane & 15, l4 = lane >> 4;

  float b1v[4], g1v[4], be1v[4], b2v[4], g2v[4], be2v[4];
  #pragma unroll
  for(int nt = 0; nt < 4; ++nt){
    int col = nt * 16 + l15;
    b1v[nt] = b1[col]; g1v[nt] = g1[col]; be1v[nt] = be1[col];
    b2v[nt] = b2[col]; g2v[nt] = g2[col]; be2v[nt] = be2[col];
  }

  // ---- GEMM1: obs @ W1 ----
  f32x4 acc1[4] = {{0,0,0,0},{0,0,0,0},{0,0,0,0},{0,0,0,0}};
  #pragma unroll
  for(int kk = 0; kk < 4; ++kk){
    s16x8 ah, al;
    build_frag(&obs[(size_t)(r0 + w * 16 + l15) * 128 + 8 * l4 + 32 * kk], ah, al);
    #pragma unroll
    for(int nt = 0; nt < 4; ++nt){
      s16x8 bh = *(const s16x8*)&w1p[(kk * 2048 + nt * 512) + lane * 8];
      s16x8 bl = *(const s16x8*)&w1p[8192 + (kk * 2048 + nt * 512) + lane * 8];
      acc1[nt] = MFMA(ah, bh, acc1[nt]);
      acc1[nt] = MFMA(ah, bl, acc1[nt]);
      acc1[nt] = MFMA(al, bh, acc1[nt]);
    }
  }

  // ---- LN1 + relu -> x1_t ----
  #pragma unroll
  for(int r = 0; r < 4; ++r){
    float v[4];
    #pragma unroll
    for(int nt = 0; nt < 4; ++nt) v[nt] = acc1[nt][r] + b1v[nt];
    float s = (v[0] + v[1]) + (v[2] + v[3]);
    #pragma unroll
    for(int mm = 1; mm < 16; mm <<= 1) s += __shfl_xor(s, mm);
    float mean = s * (1.0f / 64.0f);
    float d[4]; float q = 0.f;
    #pragma unroll
    for(int nt = 0; nt < 4; ++nt){ d[nt] = v[nt] - mean; q += d[nt] * d[nt]; }
    #pragma unroll
    for(int mm = 1; mm < 16; mm <<= 1) q += __shfl_xor(q, mm);
    float rstd = rsqrtf(q * (1.0f / 64.0f) + 1e-12f);
    int row = w * 16 + l4 * 4 + r;
    #pragma unroll
    for(int nt = 0; nt < 4; ++nt)
      x1_t[row][nt * 16 + l15] = fmaxf(0.f, d[nt] * rstd * g1v[nt] + be1v[nt]);
  }
  __syncthreads();

  // ---- GEMM2: concat(x1, act) @ W2  (kk 0,1 from x1, kk 2 from act) ----
  f32x4 acc2[4] = {{0,0,0,0},{0,0,0,0},{0,0,0,0},{0,0,0,0}};
  #pragma unroll
  for(int kk = 0; kk < 3; ++kk){
    s16x8 ah, al;
    if(kk < 2) build_frag(&x1_t[w * 16 + l15][8 * l4 + 32 * kk], ah, al);
    else       build_frag(&actg[(size_t)(r0 + w * 16 + l15) * 32 + 8 * l4], ah, al);
    #pragma unroll
    for(int nt = 0; nt < 4; ++nt){
      s16x8 bh = *(const s16x8*)&w2p[(kk * 2048 + nt * 512) + lane * 8];
      s16x8 bl = *(const s16x8*)&w2p[6144 + (kk * 2048 + nt * 512) + lane * 8];
      acc2[nt] = MFMA(ah, bh, acc2[nt]);
      acc2[nt] = MFMA(ah, bl, acc2[nt]);
      acc2[nt] = MFMA(al, bh, acc2[nt]);
    }
  }

  // ---- LN2 + relu -> split bf16 store ----
  #pragma unroll
  for(int r = 0; r < 4; ++r){
    float v[4];
    #pragma unroll
    for(int nt = 0; nt < 4; ++nt) v[nt] = acc2[nt][r] + b2v[nt];
    float s = (v[0] + v[1]) + (v[2] + v[3]);
    #pragma unroll
    for(int mm = 1; mm < 16; mm <<= 1) s += __shfl_xor(s, mm);
    float mean = s * (1.0f / 64.0f);
    float d[4]; float q = 0.f;
    #pragma unroll
    for(int nt = 0; nt < 4; ++nt){ d[nt] = v[nt] - mean; q += d[nt] * d[nt]; }
    #pragma unroll
    for(int mm = 1; mm < 16; mm <<= 1) q += __shfl_xor(q, mm);
    float rstd = rsqrtf(q * (1.0f / 64.0f) + 1e-12f);
    size_t rowg = (size_t)(r0 + w * 16 + l4 * 4 + r);
    #pragma unroll
    for(int nt = 0; nt < 4; ++nt){
      float xv = fmaxf(0.f, d[nt] * rstd * g2v[nt] + be2v[nt]);
      short hi, lo; split_hl(xv, hi, lo);
      x2h[rowg * 64 + nt * 16 + l15] = (unsigned short)hi;
      x2l[rowg * 64 + nt * 16 + l15] = (unsigned short)lo;
    }
  }
}

// ---------------------------------------------------------------------------
// Kernel 2: LSTM scan (fw & bw) + fused head.  32 sequences / block,
// 512 threads (8 waves).  W fragments loaded pre-packed from global into
// registers; h never leaves the block; xs/ps accumulate in LDS; head (LN,
// @W3, softmax, dot) computed in-block at the end.
// ---------------------------------------------------------------------------
__global__ __launch_bounds__(512) void lstm_kernel(
    const unsigned short* __restrict__ x2h, const unsigned short* __restrict__ x2l,
    const unsigned short* __restrict__ wfp, const unsigned short* __restrict__ wbp,
    const float* __restrict__ bfv, const float* __restrict__ bbv,
    const float* __restrict__ wx, const float* __restrict__ wp,
    const float* __restrict__ bx, const float* __restrict__ bp,
    const float* __restrict__ gp, const float* __restrict__ bep,
    const float* __restrict__ W3, const float* __restrict__ b3,
    float* __restrict__ out)
{
  __shared__ __align__(16) unsigned short x_lds_h[32][72];
  __shared__ __align__(16) unsigned short x_lds_l[32][72];
  __shared__ __align__(16) unsigned short h_lds_h[32][72];
  __shared__ __align__(16) unsigned short h_lds_l[32][72];
  __shared__ float xs_part[4][32];
  __shared__ float ps_part[4][32];
  __shared__ float xs_sh[32][64];
  __shared__ float ps_sh[32][64];
  __shared__ float W3s[64][64];
  __shared__ float p_sh[8][64];

  const int tid = threadIdx.x;
  const int dir = blockIdx.y;
  const int b0 = blockIdx.x * 32;
  const unsigned short* wpk  = dir ? wbp : wfp;
  const float* bias = dir ? bbv : bfv;

  const int w = tid >> 6, lane = tid & 63, l15 = lane & 15, l4 = lane >> 4;
  const int m = w >> 2, dj = w & 3;

  float biasv[4];
  #pragma unroll
  for(int gi = 0; gi < 4; ++gi) biasv[gi] = bias[gi * 64 + dj * 16 + l15];
  const float wxv = wx[dj * 16 + l15];
  const float wpv = wp[dj * 16 + l15];

  // W B-fragments (hi/lo) straight from packed global into registers.
  s16x8 Bh[4][4], Bl[4][4];
  #pragma unroll
  for(int gi = 0; gi < 4; ++gi){
    #pragma unroll
    for(int kk = 0; kk < 4; ++kk){
      int off = ((gi * 4 + kk) * 4 + dj) * 512 + lane * 8;
      Bh[gi][kk] = *(const s16x8*)&wpk[off];
      Bl[gi][kk] = *(const s16x8*)&wpk[32768 + off];
    }
  }

  // zero h state planes; stage W3 for the head
  for(int i = tid; i < 32 * 72; i += 512){ (&h_lds_h[0][0])[i] = 0; (&h_lds_l[0][0])[i] = 0; }
  for(int i = tid; i < 4096; i += 512) W3s[i >> 6][i & 63] = W3[i];

  const int s_pf = tid >> 4, c4_pf = (tid & 15) * 4;
  int t0 = dir ? 63 : 0;
  ushort4 xpre_h = *(const ushort4*)&x2h[((size_t)(b0 + s_pf) * 64 + t0) * 64 + c4_pf];
  ushort4 xpre_l = *(const ushort4*)&x2l[((size_t)(b0 + s_pf) * 64 + t0) * 64 + c4_pf];

  float c[4] = {0.f, 0.f, 0.f, 0.f};

  for(int tau = 0; tau < 64; ++tau){
    *(ushort4*)&x_lds_h[s_pf][c4_pf] = xpre_h;
    *(ushort4*)&x_lds_l[s_pf][c4_pf] = xpre_l;
    __syncthreads();
    if(tau < 63){
      int tn = dir ? 62 - tau : tau + 1;
      xpre_h = *(const ushort4*)&x2h[((size_t)(b0 + s_pf) * 64 + tn) * 64 + c4_pf];
      xpre_l = *(const ushort4*)&x2l[((size_t)(b0 + s_pf) * 64 + tn) * 64 + c4_pf];
    }
    // A fragments (pre-split, straight b128 reads)
    s16x8 Axh[2], Axl[2], Ahh[2], Ahl[2];
    #pragma unroll
    for(int kk = 0; kk < 2; ++kk){
      Axh[kk] = *(const s16x8*)&x_lds_h[m * 16 + l15][8 * l4 + 32 * kk];
      Axl[kk] = *(const s16x8*)&x_lds_l[m * 16 + l15][8 * l4 + 32 * kk];
      Ahh[kk] = *(const s16x8*)&h_lds_h[m * 16 + l15][8 * l4 + 32 * kk];
      Ahl[kk] = *(const s16x8*)&h_lds_l[m * 16 + l15][8 * l4 + 32 * kk];
    }
    f32x4 acc[4] = {{0,0,0,0},{0,0,0,0},{0,0,0,0},{0,0,0,0}};
    #pragma unroll
    for(int gi = 0; gi < 4; ++gi){
      #pragma unroll
      for(int kk = 0; kk < 2; ++kk){
        acc[gi] = MFMA(Axh[kk], Bh[gi][kk],     acc[gi]);
        acc[gi] = MFMA(Axh[kk], Bl[gi][kk],     acc[gi]);
        acc[gi] = MFMA(Axl[kk], Bh[gi][kk],     acc[gi]);
        acc[gi] = MFMA(Ahh[kk], Bh[gi][kk + 2], acc[gi]);
        acc[gi] = MFMA(Ahh[kk], Bl[gi][kk + 2], acc[gi]);
        acc[gi] = MFMA(Ahl[kk], Bh[gi][kk + 2], acc[gi]);
      }
    }
    // gates + state update (order i, j, f, o)
    float hv[4];
    #pragma unroll
    for(int r = 0; r < 4; ++r){
      float zi = acc[0][r] + biasv[0];
      float zj = acc[1][r] + biasv[1];
      float zf = acc[2][r] + biasv[2];
      float zo = acc[3][r] + biasv[3];
      float cf = c[r] * sigm(zf + 1.0f) + sigm(zi) * tanh_fast(zj);
      c[r] = cf;
      hv[r] = tanh_fast(cf) * sigm(zo);
    }
    // fold in the wx/wp dots: reduce over d (16 lanes) then across dj waves
    float px[4], pp[4];
    #pragma unroll
    for(int r = 0; r < 4; ++r){ px[r] = hv[r] * wxv; pp[r] = hv[r] * wpv; }
    #pragma unroll
    for(int mm = 1; mm < 16; mm <<= 1){
      #pragma unroll
      for(int r = 0; r < 4; ++r){ px[r] += __shfl_xor(px[r], mm); pp[r] += __shfl_xor(pp[r], mm); }
    }
    if(l15 == 0){
      #pragma unroll
      for(int r = 0; r < 4; ++r){
        int s = m * 16 + l4 * 4 + r;
        xs_part[dj][s] = px[r];
        ps_part[dj][s] = pp[r];
      }
    }
    __syncthreads();
    // write h (split bf16) for next step's A fragments
    #pragma unroll
    for(int r = 0; r < 4; ++r){
      int s = m * 16 + l4 * 4 + r;
      short hi, lo; split_hl(hv[r], hi, lo);
      h_lds_h[s][dj * 16 + l15] = (unsigned short)hi;
      h_lds_l[s][dj * 16 + l15] = (unsigned short)lo;
    }
    // deterministic cross-wave sum into LDS at time t_x
    int t_x = dir ? 63 - tau : tau;
    if(tid < 32){
      xs_sh[tid][t_x] = (xs_part[0][tid] + xs_part[1][tid]) + (xs_part[2][tid] + xs_part[3][tid]);
      ps_sh[tid][t_x] = (ps_part[0][tid] + ps_part[1][tid]) + (ps_part[2][tid] + ps_part[3][tid]);
    }
  }
  __syncthreads();

  // ---- fused head: per seq row, LN(ps) -> relu -> @W3 -> softmax -> dot xs
  const float bxv = bx[0], bpv = bp[0];
  #pragma unroll
  for(int r = 0; r < 4; ++r){
    int s = w * 4 + r;
    float xsv = xs_sh[s][lane] + bxv;
    float psv = ps_sh[s][lane] + bpv;
    float sum = psv;
    #pragma unroll
    for(int mm = 1; mm < 64; mm <<= 1) sum += __shfl_xor(sum, mm);
    float mean = sum * (1.f / 64.f);
    float d = psv - mean;
    float q = d * d;
    #pragma unroll
    for(int mm = 1; mm < 64; mm <<= 1) q += __shfl_xor(q, mm);
    float rstd = rsqrtf(q * (1.f / 64.f) + 1e-12f);
    float p = fmaxf(0.f, d * rstd * gp[lane] + bep[lane]);
    p_sh[w][lane] = p;
    float logit = b3[lane];
    #pragma unroll 8
    for(int t = 0; t < 64; ++t) logit += p_sh[w][t] * W3s[t][lane];
    float mx = logit;
    #pragma unroll
    for(int mm = 1; mm < 64; mm <<= 1) mx = fmaxf(mx, __shfl_xor(mx, mm));
    float e = __expf(logit - mx);
    float se = e;
    #pragma unroll
    for(int mm = 1; mm < 64; mm <<= 1) se += __shfl_xor(se, mm);
    float contrib = (e / se) * xsv;
    #pragma unroll
    for(int mm = 1; mm < 64; mm <<= 1) contrib += __shfl_xor(contrib, mm);
    if(lane == 0) out[(size_t)dir * 4096 + b0 + s] = contrib;
  }
}

extern "C" void kernel_launch(void* const* d_in, const int* in_sizes, int n_in,
                              void* d_out, int out_size, void* d_ws, size_t ws_size,
                              hipStream_t stream)
{
  (void)in_sizes; (void)n_in; (void)out_size; (void)ws_size;
  const float* obs = (const float*)d_in[0];
  const float* act = (const float*)d_in[1];
  const float* W1  = (const float*)d_in[2];
  const float* b1  = (const float*)d_in[3];
  const float* g1  = (const float*)d_in[4];
  const float* be1 = (const float*)d_in[5];
  const float* W2  = (const float*)d_in[6];
  const float* b2  = (const float*)d_in[7];
  const float* g2  = (const float*)d_in[8];
  const float* be2 = (const float*)d_in[9];
  const float* Wf  = (const float*)d_in[10];
  const float* bfv = (const float*)d_in[11];
  const float* Wb  = (const float*)d_in[12];
  const float* bbv = (const float*)d_in[13];
  const float* wx  = (const float*)d_in[14];
  const float* bx  = (const float*)d_in[15];
  const float* wp  = (const float*)d_in[16];
  const float* bp  = (const float*)d_in[17];
  const float* gp  = (const float*)d_in[18];
  const float* bep = (const float*)d_in[19];
  const float* W3  = (const float*)d_in[20];
  const float* b3  = (const float*)d_in[21];

  unsigned short* x2h = (unsigned short*)d_ws;                 // 262144*64 shorts
  unsigned short* x2l = x2h + (size_t)262144 * 64;             // 262144*64 shorts
  unsigned short* w1p = x2l + (size_t)262144 * 64;             // 2*8192
  unsigned short* w2p = w1p + 2 * 8192;                        // 2*6144
  unsigned short* wfp = w2p + 2 * 6144;                        // 2*32768
  unsigned short* wbp = wfp + 2 * 32768;                       // 2*32768
  float* outf = (float*)d_out;

  pack_kernel<<<312, 256, 0, stream>>>(W1, W2, Wf, Wb, w1p, w2p, wfp, wbp);
  trunk_kernel<<<4096, 256, 0, stream>>>(obs, act, b1, g1, be1, b2, g2, be2, w1p, w2p, x2h, x2l);
  lstm_kernel<<<dim3(128, 2), 512, 0, stream>>>(x2h, x2l, wfp, wbp, bfv, bbv, wx, wp,
                                                bx, bp, gp, bep, W3, b3, outf);
}

// Round 4
// 176.716 us; speedup vs baseline: 2.3862x; 1.4015x over previous
//
#include <hip/hip_runtime.h>
#include <hip/hip_bf16.h>

typedef __attribute__((ext_vector_type(8))) short s16x8;
typedef __attribute__((ext_vector_type(4))) float f32x4;

#define MFMA(a,b,c) __builtin_amdgcn_mfma_f32_16x16x32_bf16((a),(b),(c),0,0,0)

__device__ __forceinline__ unsigned short bf16_rne(float f){
  unsigned int u = __float_as_uint(f);
  return (unsigned short)((u + 0x7FFFu + ((u >> 16) & 1u)) >> 16);
}
__device__ __forceinline__ float bf16_f32(unsigned short h){
  return __uint_as_float(((unsigned int)h) << 16);
}
__device__ __forceinline__ void split_hl(float f, short& hi, short& lo){
  unsigned short h = bf16_rne(f);
  float rem = f - bf16_f32(h);
  hi = (short)h;
  lo = (short)bf16_rne(rem);
}

__device__ __forceinline__ void build_frag(const float* p, s16x8& fh, s16x8& fl){
  float4 v0 = *(const float4*)p;
  float4 v1 = *(const float4*)(p + 4);
  float vv[8] = {v0.x, v0.y, v0.z, v0.w, v1.x, v1.y, v1.z, v1.w};
  #pragma unroll
  for(int j = 0; j < 8; ++j){ short h, l; split_hl(vv[j], h, l); fh[j] = h; fl[j] = l; }
}

__device__ __forceinline__ float sigm(float x){
  return __builtin_amdgcn_rcpf(1.0f + __expf(-x));
}
__device__ __forceinline__ float tanh_fast(float x){
  return 1.0f - 2.0f * __builtin_amdgcn_rcpf(__expf(2.0f * x) + 1.0f);
}

// sum over the 16 lanes of each row-of-16 via DPP butterfly (VALU only).
__device__ __forceinline__ float red16(float x){
  int v;
  v = __builtin_amdgcn_update_dpp(0, __float_as_int(x), 0xB1, 0xF, 0xF, true);  // quad_perm xor1
  x += __int_as_float(v);
  v = __builtin_amdgcn_update_dpp(0, __float_as_int(x), 0x4E, 0xF, 0xF, true);  // quad_perm xor2
  x += __int_as_float(v);
  v = __builtin_amdgcn_update_dpp(0, __float_as_int(x), 0x141, 0xF, 0xF, true); // row_half_mirror
  x += __int_as_float(v);
  v = __builtin_amdgcn_update_dpp(0, __float_as_int(x), 0x140, 0xF, 0xF, true); // row_mirror
  x += __int_as_float(v);
  return x;
}

// ---------------------------------------------------------------------------
// Kernel 0: pack weights into fragment-ordered split-bf16 planes (once).
// ---------------------------------------------------------------------------
__global__ __launch_bounds__(256) void pack_kernel(
    const float* __restrict__ W1, const float* __restrict__ W2,
    const float* __restrict__ Wf, const float* __restrict__ Wb,
    unsigned short* __restrict__ w1p, unsigned short* __restrict__ w2p,
    unsigned short* __restrict__ wfp, unsigned short* __restrict__ wbp)
{
  int id = blockIdx.x * 256 + threadIdx.x;
  if(id < 8192){
    int t = id;
    int j = t & 7, lane = (t >> 3) & 63, nt = (t >> 9) & 3, kk = t >> 11;
    int k = kk * 32 + 8 * (lane >> 4) + j;
    int col = nt * 16 + (lane & 15);
    short h, l; split_hl(W1[k * 64 + col], h, l);
    w1p[t] = (unsigned short)h; w1p[8192 + t] = (unsigned short)l;
  } else if(id < 14336){
    int t = id - 8192;
    int j = t & 7, lane = (t >> 3) & 63, nt = (t >> 9) & 3, kk = t >> 11;
    int k = kk * 32 + 8 * (lane >> 4) + j;
    int col = nt * 16 + (lane & 15);
    short h, l; split_hl(W2[k * 64 + col], h, l);
    w2p[t] = (unsigned short)h; w2p[6144 + t] = (unsigned short)l;
  } else if(id < 47104){
    int t = id - 14336;
    int j = t & 7, lane = (t >> 3) & 63, dj = (t >> 9) & 3, kk = (t >> 11) & 3, gi = t >> 13;
    int k = kk * 32 + 8 * (lane >> 4) + j;
    int col = gi * 64 + dj * 16 + (lane & 15);
    short h, l; split_hl(Wf[k * 256 + col], h, l);
    wfp[t] = (unsigned short)h; wfp[32768 + t] = (unsigned short)l;
  } else if(id < 79872){
    int t = id - 47104;
    int j = t & 7, lane = (t >> 3) & 63, dj = (t >> 9) & 3, kk = (t >> 11) & 3, gi = t >> 13;
    int k = kk * 32 + 8 * (lane >> 4) + j;
    int col = gi * 64 + dj * 16 + (lane & 15);
    short h, l; split_hl(Wb[k * 256 + col], h, l);
    wbp[t] = (unsigned short)h; wbp[32768 + t] = (unsigned short)l;
  }
}

// ---------------------------------------------------------------------------
// Kernel 1: trunk (unchanged from R2).
// ---------------------------------------------------------------------------
__global__ __launch_bounds__(256) void trunk_kernel(
    const float* __restrict__ obs, const float* __restrict__ actg,
    const float* __restrict__ b1, const float* __restrict__ g1, const float* __restrict__ be1,
    const float* __restrict__ b2, const float* __restrict__ g2, const float* __restrict__ be2,
    const unsigned short* __restrict__ w1p, const unsigned short* __restrict__ w2p,
    unsigned short* __restrict__ x2h, unsigned short* __restrict__ x2l)
{
  __shared__ __align__(16) float x1_t[64][68];

  const int tid = threadIdx.x;
  const int r0 = blockIdx.x * 64;
  const int w = tid >> 6, lane = tid & 63;
  const int l15 = lane & 15, l4 = lane >> 4;

  float b1v[4], g1v[4], be1v[4], b2v[4], g2v[4], be2v[4];
  #pragma unroll
  for(int nt = 0; nt < 4; ++nt){
    int col = nt * 16 + l15;
    b1v[nt] = b1[col]; g1v[nt] = g1[col]; be1v[nt] = be1[col];
    b2v[nt] = b2[col]; g2v[nt] = g2[col]; be2v[nt] = be2[col];
  }

  f32x4 acc1[4] = {{0,0,0,0},{0,0,0,0},{0,0,0,0},{0,0,0,0}};
  #pragma unroll
  for(int kk = 0; kk < 4; ++kk){
    s16x8 ah, al;
    build_frag(&obs[(size_t)(r0 + w * 16 + l15) * 128 + 8 * l4 + 32 * kk], ah, al);
    #pragma unroll
    for(int nt = 0; nt < 4; ++nt){
      s16x8 bh = *(const s16x8*)&w1p[(kk * 2048 + nt * 512) + lane * 8];
      s16x8 bl = *(const s16x8*)&w1p[8192 + (kk * 2048 + nt * 512) + lane * 8];
      acc1[nt] = MFMA(ah, bh, acc1[nt]);
      acc1[nt] = MFMA(ah, bl, acc1[nt]);
      acc1[nt] = MFMA(al, bh, acc1[nt]);
    }
  }

  #pragma unroll
  for(int r = 0; r < 4; ++r){
    float v[4];
    #pragma unroll
    for(int nt = 0; nt < 4; ++nt) v[nt] = acc1[nt][r] + b1v[nt];
    float s = (v[0] + v[1]) + (v[2] + v[3]);
    #pragma unroll
    for(int mm = 1; mm < 16; mm <<= 1) s += __shfl_xor(s, mm);
    float mean = s * (1.0f / 64.0f);
    float d[4]; float q = 0.f;
    #pragma unroll
    for(int nt = 0; nt < 4; ++nt){ d[nt] = v[nt] - mean; q += d[nt] * d[nt]; }
    #pragma unroll
    for(int mm = 1; mm < 16; mm <<= 1) q += __shfl_xor(q, mm);
    float rstd = rsqrtf(q * (1.0f / 64.0f) + 1e-12f);
    int row = w * 16 + l4 * 4 + r;
    #pragma unroll
    for(int nt = 0; nt < 4; ++nt)
      x1_t[row][nt * 16 + l15] = fmaxf(0.f, d[nt] * rstd * g1v[nt] + be1v[nt]);
  }
  __syncthreads();

  f32x4 acc2[4] = {{0,0,0,0},{0,0,0,0},{0,0,0,0},{0,0,0,0}};
  #pragma unroll
  for(int kk = 0; kk < 3; ++kk){
    s16x8 ah, al;
    if(kk < 2) build_frag(&x1_t[w * 16 + l15][8 * l4 + 32 * kk], ah, al);
    else       build_frag(&actg[(size_t)(r0 + w * 16 + l15) * 32 + 8 * l4], ah, al);
    #pragma unroll
    for(int nt = 0; nt < 4; ++nt){
      s16x8 bh = *(const s16x8*)&w2p[(kk * 2048 + nt * 512) + lane * 8];
      s16x8 bl = *(const s16x8*)&w2p[6144 + (kk * 2048 + nt * 512) + lane * 8];
      acc2[nt] = MFMA(ah, bh, acc2[nt]);
      acc2[nt] = MFMA(ah, bl, acc2[nt]);
      acc2[nt] = MFMA(al, bh, acc2[nt]);
    }
  }

  #pragma unroll
  for(int r = 0; r < 4; ++r){
    float v[4];
    #pragma unroll
    for(int nt = 0; nt < 4; ++nt) v[nt] = acc2[nt][r] + b2v[nt];
    float s = (v[0] + v[1]) + (v[2] + v[3]);
    #pragma unroll
    for(int mm = 1; mm < 16; mm <<= 1) s += __shfl_xor(s, mm);
    float mean = s * (1.0f / 64.0f);
    float d[4]; float q = 0.f;
    #pragma unroll
    for(int nt = 0; nt < 4; ++nt){ d[nt] = v[nt] - mean; q += d[nt] * d[nt]; }
    #pragma unroll
    for(int mm = 1; mm < 16; mm <<= 1) q += __shfl_xor(q, mm);
    float rstd = rsqrtf(q * (1.0f / 64.0f) + 1e-12f);
    size_t rowg = (size_t)(r0 + w * 16 + l4 * 4 + r);
    #pragma unroll
    for(int nt = 0; nt < 4; ++nt){
      float xv = fmaxf(0.f, d[nt] * rstd * g2v[nt] + be2v[nt]);
      short hi, lo; split_hl(xv, hi, lo);
      x2h[rowg * 64 + nt * 16 + l15] = (unsigned short)hi;
      x2l[rowg * 64 + nt * 16 + l15] = (unsigned short)lo;
    }
  }
}

// ---------------------------------------------------------------------------
// Kernel 2: LSTM scan + fused head.  16 sequences / block, 256 threads
// (4 waves, wave = dj col-slice).  Single barrier per step: h double-buffered
// in LDS; x A-fragments prefetched from global into ping-pong registers;
// W fragments register-resident; dots via DPP reduce, pipelined 1 step.
// ---------------------------------------------------------------------------
__global__ __launch_bounds__(256, 2) void lstm_kernel(
    const unsigned short* __restrict__ x2h, const unsigned short* __restrict__ x2l,
    const unsigned short* __restrict__ wfp, const unsigned short* __restrict__ wbp,
    const float* __restrict__ bfv, const float* __restrict__ bbv,
    const float* __restrict__ wx, const float* __restrict__ wp,
    const float* __restrict__ bx, const float* __restrict__ bp,
    const float* __restrict__ gp, const float* __restrict__ bep,
    const float* __restrict__ W3, const float* __restrict__ b3,
    float* __restrict__ out)
{
  __shared__ __align__(16) unsigned short h_h[2][16][72];
  __shared__ __align__(16) unsigned short h_l[2][16][72];
  __shared__ float xs_part[2][4][16];
  __shared__ float ps_part[2][4][16];
  __shared__ float xs_sh[16][64];
  __shared__ float ps_sh[16][64];
  __shared__ float W3s[64][64];
  __shared__ float p_sh[4][64];

  const int tid = threadIdx.x;
  const int dir = blockIdx.y;
  const int b0 = blockIdx.x * 16;
  const unsigned short* wpk  = dir ? wbp : wfp;
  const float* bias = dir ? bbv : bfv;

  const int w = tid >> 6, lane = tid & 63, l15 = lane & 15, l4 = lane >> 4;
  const int dj = w;

  float biasv[4];
  #pragma unroll
  for(int gi = 0; gi < 4; ++gi) biasv[gi] = bias[gi * 64 + dj * 16 + l15];
  biasv[2] += 1.0f;                       // forget_bias folded in
  const float wxv = wx[dj * 16 + l15];
  const float wpv = wp[dj * 16 + l15];

  // W B-fragments (hi/lo) register-resident for all 64 steps.
  s16x8 Bh[4][4], Bl[4][4];
  #pragma unroll
  for(int gi = 0; gi < 4; ++gi){
    #pragma unroll
    for(int kk = 0; kk < 4; ++kk){
      int off = ((gi * 4 + kk) * 4 + dj) * 512 + lane * 8;
      Bh[gi][kk] = *(const s16x8*)&wpk[off];
      Bl[gi][kk] = *(const s16x8*)&wpk[32768 + off];
    }
  }

  // stage W3 (head), zero h buffer 0
  #pragma unroll
  for(int i = 0; i < 4; ++i)
    *(float4*)&W3s[0][tid * 16 + i * 4] = *(const float4*)&W3[tid * 16 + i * 4];
  for(int i = tid; i < 16 * 72; i += 256){
    (&h_h[0][0][0])[i] = 0; (&h_l[0][0][0])[i] = 0;
  }

  // per-lane global x base: seq = b0+l15, k-chunk = 8*l4 (+32 for kk=1)
  const unsigned short* xbh = x2h + (size_t)(b0 + l15) * 4096 + 8 * l4;
  const unsigned short* xbl = x2l + (size_t)(b0 + l15) * 4096 + 8 * l4;

  int t0 = dir ? 63 : 0;
  int t1 = dir ? 62 : 1;
  s16x8 xah  = *(const s16x8*)&xbh[t0 * 64];
  s16x8 xah2 = *(const s16x8*)&xbh[t0 * 64 + 32];
  s16x8 xal  = *(const s16x8*)&xbl[t0 * 64];
  s16x8 xal2 = *(const s16x8*)&xbl[t0 * 64 + 32];
  s16x8 xbhr = *(const s16x8*)&xbh[t1 * 64];
  s16x8 xbh2 = *(const s16x8*)&xbh[t1 * 64 + 32];
  s16x8 xblr = *(const s16x8*)&xbl[t1 * 64];
  s16x8 xbl2 = *(const s16x8*)&xbl[t1 * 64 + 32];

  float c[4] = {0.f, 0.f, 0.f, 0.f};

  __syncthreads();   // h zero + W3 staged

  auto lstm_step = [&](s16x8& XH0, s16x8& XH1, s16x8& XL0, s16x8& XL1, int tau){
    const int cb = tau & 1, nb = cb ^ 1;
    // drain previous step's dot partials (pipelined)
    if(tau > 0 && tid < 16){
      int pb = nb;  // (tau-1)&1
      int tp = dir ? 64 - tau : tau - 1;
      xs_sh[tid][tp] = (xs_part[pb][0][tid] + xs_part[pb][1][tid])
                     + (xs_part[pb][2][tid] + xs_part[pb][3][tid]);
      ps_sh[tid][tp] = (ps_part[pb][0][tid] + ps_part[pb][1][tid])
                     + (ps_part[pb][2][tid] + ps_part[pb][3][tid]);
    }
    // h A-fragments from current buffer
    s16x8 Ahh0 = *(const s16x8*)&h_h[cb][l15][8 * l4];
    s16x8 Ahh1 = *(const s16x8*)&h_h[cb][l15][8 * l4 + 32];
    s16x8 Ahl0 = *(const s16x8*)&h_l[cb][l15][8 * l4];
    s16x8 Ahl1 = *(const s16x8*)&h_l[cb][l15][8 * l4 + 32];
    f32x4 acc[4];
    #pragma unroll
    for(int gi = 0; gi < 4; ++gi)
      acc[gi] = (f32x4){biasv[gi], biasv[gi], biasv[gi], biasv[gi]};
    #pragma unroll
    for(int gi = 0; gi < 4; ++gi){
      acc[gi] = MFMA(XH0, Bh[gi][0], acc[gi]);
      acc[gi] = MFMA(XH0, Bl[gi][0], acc[gi]);
      acc[gi] = MFMA(XL0, Bh[gi][0], acc[gi]);
      acc[gi] = MFMA(XH1, Bh[gi][1], acc[gi]);
      acc[gi] = MFMA(XH1, Bl[gi][1], acc[gi]);
      acc[gi] = MFMA(XL1, Bh[gi][1], acc[gi]);
    }
    // prefetch x for step tau+2 into the just-consumed registers
    {
      int tf = tau + 2; if(tf > 63) tf = 63;
      int tn = dir ? 63 - tf : tf;
      XH0 = *(const s16x8*)&xbh[tn * 64];
      XH1 = *(const s16x8*)&xbh[tn * 64 + 32];
      XL0 = *(const s16x8*)&xbl[tn * 64];
      XL1 = *(const s16x8*)&xbl[tn * 64 + 32];
    }
    #pragma unroll
    for(int gi = 0; gi < 4; ++gi){
      acc[gi] = MFMA(Ahh0, Bh[gi][2], acc[gi]);
      acc[gi] = MFMA(Ahh0, Bl[gi][2], acc[gi]);
      acc[gi] = MFMA(Ahl0, Bh[gi][2], acc[gi]);
      acc[gi] = MFMA(Ahh1, Bh[gi][3], acc[gi]);
      acc[gi] = MFMA(Ahh1, Bl[gi][3], acc[gi]);
      acc[gi] = MFMA(Ahl1, Bh[gi][3], acc[gi]);
    }
    float hv[4];
    #pragma unroll
    for(int r = 0; r < 4; ++r){
      float zi = acc[0][r];
      float zj = acc[1][r];
      float zf = acc[2][r];
      float zo = acc[3][r];
      float cf = c[r] * sigm(zf) + sigm(zi) * tanh_fast(zj);
      c[r] = cf;
      hv[r] = tanh_fast(cf) * sigm(zo);
    }
    // write h (split) into next buffer
    #pragma unroll
    for(int r = 0; r < 4; ++r){
      int s = l4 * 4 + r;
      short hi, lo; split_hl(hv[r], hi, lo);
      h_h[nb][s][dj * 16 + l15] = (unsigned short)hi;
      h_l[nb][s][dj * 16 + l15] = (unsigned short)lo;
    }
    // wx/wp dots: DPP reduce over the 16 d-lanes, store per-wave partial
    #pragma unroll
    for(int r = 0; r < 4; ++r){
      float px = red16(hv[r] * wxv);
      float pp = red16(hv[r] * wpv);
      if(l15 == 0){
        int s = l4 * 4 + r;
        xs_part[cb][dj][s] = px;
        ps_part[cb][dj][s] = pp;
      }
    }
    __syncthreads();
  };

  for(int tau = 0; tau < 64; tau += 2){
    lstm_step(xah, xah2, xal, xal2, tau);
    lstm_step(xbhr, xbh2, xblr, xbl2, tau + 1);
  }

  // drain last step's partials
  if(tid < 16){
    int tp = dir ? 0 : 63;
    xs_sh[tid][tp] = (xs_part[1][0][tid] + xs_part[1][1][tid])
                   + (xs_part[1][2][tid] + xs_part[1][3][tid]);
    ps_sh[tid][tp] = (ps_part[1][0][tid] + ps_part[1][1][tid])
                   + (ps_part[1][2][tid] + ps_part[1][3][tid]);
  }
  __syncthreads();

  // ---- fused head ----
  const float bxv = bx[0], bpv = bp[0];
  #pragma unroll
  for(int r = 0; r < 4; ++r){
    int s = w * 4 + r;
    float xsv = xs_sh[s][lane] + bxv;
    float psv = ps_sh[s][lane] + bpv;
    float sum = psv;
    #pragma unroll
    for(int mm = 1; mm < 64; mm <<= 1) sum += __shfl_xor(sum, mm);
    float mean = sum * (1.f / 64.f);
    float d = psv - mean;
    float q = d * d;
    #pragma unroll
    for(int mm = 1; mm < 64; mm <<= 1) q += __shfl_xor(q, mm);
    float rstd = rsqrtf(q * (1.f / 64.f) + 1e-12f);
    float p = fmaxf(0.f, d * rstd * gp[lane] + bep[lane]);
    p_sh[w][lane] = p;
    float logit = b3[lane];
    #pragma unroll 8
    for(int t = 0; t < 64; ++t) logit += p_sh[w][t] * W3s[t][lane];
    float mx = logit;
    #pragma unroll
    for(int mm = 1; mm < 64; mm <<= 1) mx = fmaxf(mx, __shfl_xor(mx, mm));
    float e = __expf(logit - mx);
    float se = e;
    #pragma unroll
    for(int mm = 1; mm < 64; mm <<= 1) se += __shfl_xor(se, mm);
    float contrib = (e / se) * xsv;
    #pragma unroll
    for(int mm = 1; mm < 64; mm <<= 1) contrib += __shfl_xor(contrib, mm);
    if(lane == 0) out[(size_t)dir * 4096 + b0 + s] = contrib;
  }
}

extern "C" void kernel_launch(void* const* d_in, const int* in_sizes, int n_in,
                              void* d_out, int out_size, void* d_ws, size_t ws_size,
                              hipStream_t stream)
{
  (void)in_sizes; (void)n_in; (void)out_size; (void)ws_size;
  const float* obs = (const float*)d_in[0];
  const float* act = (const float*)d_in[1];
  const float* W1  = (const float*)d_in[2];
  const float* b1  = (const float*)d_in[3];
  const float* g1  = (const float*)d_in[4];
  const float* be1 = (const float*)d_in[5];
  const float* W2  = (const float*)d_in[6];
  const float* b2  = (const float*)d_in[7];
  const float* g2  = (const float*)d_in[8];
  const float* be2 = (const float*)d_in[9];
  const float* Wf  = (const float*)d_in[10];
  const float* bfv = (const float*)d_in[11];
  const float* Wb  = (const float*)d_in[12];
  const float* bbv = (const float*)d_in[13];
  const float* wx  = (const float*)d_in[14];
  const float* bx  = (const float*)d_in[15];
  const float* wp  = (const float*)d_in[16];
  const float* bp  = (const float*)d_in[17];
  const float* gp  = (const float*)d_in[18];
  const float* bep = (const float*)d_in[19];
  const float* W3  = (const float*)d_in[20];
  const float* b3  = (const float*)d_in[21];

  unsigned short* x2h = (unsigned short*)d_ws;                 // 262144*64 shorts
  unsigned short* x2l = x2h + (size_t)262144 * 64;             // 262144*64 shorts
  unsigned short* w1p = x2l + (size_t)262144 * 64;             // 2*8192
  unsigned short* w2p = w1p + 2 * 8192;                        // 2*6144
  unsigned short* wfp = w2p + 2 * 6144;                        // 2*32768
  unsigned short* wbp = wfp + 2 * 32768;                       // 2*32768
  float* outf = (float*)d_out;

  pack_kernel<<<312, 256, 0, stream>>>(W1, W2, Wf, Wb, w1p, w2p, wfp, wbp);
  trunk_kernel<<<4096, 256, 0, stream>>>(obs, act, b1, g1, be1, b2, g2, be2, w1p, w2p, x2h, x2l);
  lstm_kernel<<<dim3(256, 2), 256, 0, stream>>>(x2h, x2l, wfp, wbp, bfv, bbv, wx, wp,
                                                bx, bp, gp, bep, W3, b3, outf);
}